// Round 9
// baseline (3917.785 us; speedup 1.0000x reference)
//
#include <hip/hip_runtime.h>
#include <hip/hip_cooperative_groups.h>

namespace cg = cooperative_groups;

// SSGC: h = alpha*x0 + (1-alpha)/K * sum_{k=1..K} (D^-1/2 A_hat D^-1/2)^k x0 ; out = h W^T + b
// N=50000, E=1.6M, D=128, K=16, alpha=0.05.
// R9: cooperative persistent-hop kernel WITH CHECKED LAUNCH; on launch error falls back to
//     the proven R7 multi-launch path (identical buffers/semantics). bf16 feature rows,
//     stepped gather tails, packed 8B edge records, register-resident h in coop path.

#define N_NODES 50000
#define N_EDGES 1600000
#define D 128
#define K_HOPS 16
#define ALPHA 0.05f
#define HCOEF ((1.0f - ALPHA) / (float)K_HOPS)

#define NBLOCKS 625           // 625 blocks x 4 waves x 20 nodes = 50000 exactly
#define NODES_PER_WAVE 20

__device__ __forceinline__ unsigned int f2bf(float f) {
    unsigned int u = __float_as_uint(f);
    return (u + 0x7FFFu + ((u >> 16) & 1u)) >> 16;   // RNE
}
__device__ __forceinline__ unsigned int pack_bf2(float x, float y) {
    return f2bf(x) | (f2bf(y) << 16);
}
__device__ __forceinline__ float bf_lo(unsigned int w) { return __uint_as_float(w << 16); }
__device__ __forceinline__ float bf_hi(unsigned int w) { return __uint_as_float(w & 0xFFFF0000u); }

// Count in-degree and assign each edge its within-destination rank (coalesced write).
__global__ void deg_kernel(const int* __restrict__ dst, int* __restrict__ deg,
                           int* __restrict__ rank, int e) {
    int i = blockIdx.x * blockDim.x + threadIdx.x;
    if (i < e) rank[i] = atomicAdd(&deg[dst[i]], 1);
}

// dinv = 1/sqrt(deg+1); selfw = dinv^2 (self-loop weight)
__global__ void dinv_kernel(const int* __restrict__ deg, float* __restrict__ dinv,
                            float* __restrict__ selfw, int n) {
    int i = blockIdx.x * blockDim.x + threadIdx.x;
    if (i < n) {
        float di = rsqrtf((float)(deg[i] + 1));
        dinv[i] = di;
        selfw[i] = di * di;
    }
}

// Exclusive scan of deg -> row_start. Single block, 1024 threads, shfl wave scans.
__global__ void scan_kernel(const int* __restrict__ deg, int* __restrict__ row_start, int n) {
    __shared__ int wsum[16];
    __shared__ int tot_s;
    __shared__ int carry_s;
    int tid = threadIdx.x, lane = tid & 63, wid = tid >> 6;
    if (tid == 0) carry_s = 0;
    __syncthreads();
    for (int base = 0; base < n; base += 1024) {
        int i = base + tid;
        int v = (i < n) ? deg[i] : 0;
        int s = v;
        #pragma unroll
        for (int off = 1; off < 64; off <<= 1) {
            int t = __shfl_up(s, off, 64);
            if (lane >= off) s += t;
        }
        if (lane == 63) wsum[wid] = s;
        __syncthreads();                       // (A) wsum ready
        if (tid == 0) {
            int run = 0;
            #pragma unroll
            for (int w = 0; w < 16; ++w) { int t = wsum[w]; wsum[w] = run; run += t; }
            tot_s = run;
        }
        __syncthreads();                       // (B) offsets ready, carry stable
        if (i < n) row_start[i] = carry_s + wsum[wid] + (s - v);
        __syncthreads();                       // (C) all reads of carry_s done
        if (tid == 0) carry_s += tot_s;
    }
    __syncthreads();
    if (tid == 0) row_start[n] = carry_s;
}

// One 8B scattered store per edge: record = (src, bitcast(norm weight)).
__global__ void scatter_kernel(const int* __restrict__ src, const int* __restrict__ dst,
                               const int* __restrict__ rank,
                               const int* __restrict__ row_start, int2* __restrict__ csr,
                               const float* __restrict__ dinv, int e) {
    int i = blockIdx.x * blockDim.x + threadIdx.x;
    if (i < e) {
        int d = dst[i];
        int s = src[i];
        int pos = row_start[d] + rank[i];
        csr[pos] = make_int2(s, __float_as_int(dinv[d] * dinv[s]));
    }
}

// x0 -> packed bf16 x; h = alpha * x0 (exact f32). (fallback path)
__global__ void init_kernel(const float2* __restrict__ x0, unsigned int* __restrict__ xb,
                            float2* __restrict__ h, int n2) {
    int i = blockIdx.x * blockDim.x + threadIdx.x;
    if (i < n2) {
        float2 v = x0[i];
        xb[i] = pack_bf2(v.x, v.y);
        h[i] = make_float2(ALPHA * v.x, ALPHA * v.y);
    }
}

#define GATHER_BLOCK(SRCBUF, W)                                                 \
    {                                                                           \
        unsigned int g[W];                                                      \
        float wv[W];                                                            \
        _Pragma("unroll") for (int q = 0; q < W; ++q) {                         \
            int s = __shfl(rec.x, j + q);                                       \
            wv[q] = __int_as_float(__shfl(rec.y, j + q));                       \
            g[q] = SRCBUF[(size_t)s * 64 + lane];                               \
        }                                                                       \
        _Pragma("unroll") for (int q = 0; q < W; ++q) {                         \
            accx += wv[q] * bf_lo(g[q]);                                        \
            accy += wv[q] * bf_hi(g[q]);                                        \
        }                                                                       \
        j += W;                                                                 \
    }

// ---------- Fallback (R7-proven): one launch per hop ----------
__global__ __launch_bounds__(256) void agg_kernel(
    const unsigned int* __restrict__ xb, unsigned int* __restrict__ yb,
    float2* __restrict__ h2, const float* __restrict__ selfw,
    const int* __restrict__ row_start, const int2* __restrict__ csr, int update_h) {
    int wid = threadIdx.x >> 6;
    int lane = threadIdx.x & 63;
    int node = blockIdx.x * 4 + wid;
    if (node >= N_NODES) return;

    int r0 = row_start[node];
    int r1 = row_start[node + 1];
    int deg = r1 - r0;
    size_t o = (size_t)node * 64 + lane;

    unsigned int vw = xb[o];
    float sw = selfw[node];
    float accx = sw * bf_lo(vw), accy = sw * bf_hi(vw);

    for (int base = 0; base < deg; base += 64) {
        int cnt = deg - base;
        if (cnt > 64) cnt = 64;
        int idx = r0 + base + lane;
        if (idx >= r1) idx = r1 - 1;           // clamped lanes are never shfl-read
        int2 rec = csr[idx];

        int j = 0;
        while (j + 16 <= cnt) GATHER_BLOCK(xb, 16);
        if (j + 8 <= cnt) GATHER_BLOCK(xb, 8);
        if (j + 4 <= cnt) GATHER_BLOCK(xb, 4);
        for (; j < cnt; ++j) {
            int s = __shfl(rec.x, j);
            float w = __int_as_float(__shfl(rec.y, j));
            unsigned int gw = xb[(size_t)s * 64 + lane];
            accx += w * bf_lo(gw);
            accy += w * bf_hi(gw);
        }
    }

    yb[o] = pack_bf2(accx, accy);
    if (update_h) {
        float2 hv = h2[o];
        hv.x += HCOEF * (bf_lo(vw) + accx);    // x_k (rounded) + x_{k+1} (pre-round)
        hv.y += HCOEF * (bf_hi(vw) + accy);
        h2[o] = hv;
    }
}

// ---------- Cooperative persistent-hop kernel ----------
__global__ __launch_bounds__(256, 3) void hops_kernel(
    const float2* __restrict__ x0, unsigned int* __restrict__ xa,
    unsigned int* __restrict__ xb, float2* __restrict__ hout,
    const float* __restrict__ selfw, const int* __restrict__ row_start,
    const int2* __restrict__ csr) {
    cg::grid_group grid = cg::this_grid();
    int gwave = (int)((blockIdx.x * 256 + threadIdx.x) >> 6);   // 0..2499
    int lane = threadIdx.x & 63;
    int node0 = gwave * NODES_PER_WAVE;

    float hx[NODES_PER_WAVE], hy[NODES_PER_WAVE];   // f32 h accumulator (registers)
    float px[NODES_PER_WAVE], py[NODES_PER_WAVE];   // f32 x_k for the self term

    #pragma unroll
    for (int n = 0; n < NODES_PER_WAVE; ++n) {
        int node = node0 + n;
        float2 v = x0[(size_t)node * 64 + lane];
        px[n] = v.x; py[n] = v.y;
        hx[n] = ALPHA * v.x; hy[n] = ALPHA * v.y;
        xa[(size_t)node * 64 + lane] = pack_bf2(v.x, v.y);
    }
    __threadfence();
    grid.sync();

    unsigned int* cur = xa;
    unsigned int* nxt = xb;
    for (int k = 0; k < K_HOPS; ++k) {
        #pragma unroll
        for (int n = 0; n < NODES_PER_WAVE; ++n) {
            int node = node0 + n;
            int r0 = row_start[node];
            int r1 = row_start[node + 1];
            int deg = r1 - r0;
            float sw = selfw[node];
            float accx = sw * px[n], accy = sw * py[n];

            for (int base = 0; base < deg; base += 64) {
                int cnt = deg - base;
                if (cnt > 64) cnt = 64;
                int idx = r0 + base + lane;
                if (idx >= r1) idx = r1 - 1;
                int2 rec = csr[idx];

                int j = 0;
                while (j + 16 <= cnt) GATHER_BLOCK(cur, 16);
                if (j + 8 <= cnt) GATHER_BLOCK(cur, 8);
                if (j + 4 <= cnt) GATHER_BLOCK(cur, 4);
                for (; j < cnt; ++j) {
                    int s = __shfl(rec.x, j);
                    float w = __int_as_float(__shfl(rec.y, j));
                    unsigned int gw = cur[(size_t)s * 64 + lane];
                    accx += w * bf_lo(gw);
                    accy += w * bf_hi(gw);
                }
            }

            hx[n] += HCOEF * accx;
            hy[n] += HCOEF * accy;
            px[n] = accx; py[n] = accy;
            nxt[(size_t)node * 64 + lane] = pack_bf2(accx, accy);
        }
        __threadfence();
        grid.sync();
        unsigned int* t = cur; cur = nxt; nxt = t;
    }

    #pragma unroll
    for (int n = 0; n < NODES_PER_WAVE; ++n) {
        int node = node0 + n;
        hout[(size_t)node * 64 + lane] = make_float2(hx[n], hy[n]);
    }
}

// out[r][c] = sum_k h[r][k]*W[c][k] + bias[c]. h and out are DIFFERENT buffers.
__global__ __launch_bounds__(256) void gemm_kernel(
    const float* __restrict__ h, const float* __restrict__ w,
    const float* __restrict__ bias, float* __restrict__ out) {
    __shared__ float sAT[128][64];   // [k][row]
    __shared__ float sBT[128][64];   // [k][col]
    int tid = threadIdx.x;
    int row0 = blockIdx.x * 64;
    int col0 = blockIdx.y * 64;

    for (int idx = tid; idx < 64 * 32; idx += 256) {
        int r = idx & 63, kq = idx >> 6;
        float4 v;
        if (row0 + r < N_NODES)
            v = *(const float4*)&h[(size_t)(row0 + r) * D + kq * 4];
        else
            v = make_float4(0.f, 0.f, 0.f, 0.f);
        sAT[kq * 4 + 0][r] = v.x;
        sAT[kq * 4 + 1][r] = v.y;
        sAT[kq * 4 + 2][r] = v.z;
        sAT[kq * 4 + 3][r] = v.w;
    }
    for (int idx = tid; idx < 64 * 32; idx += 256) {
        int c = idx & 63, kq = idx >> 6;
        float4 v = *(const float4*)&w[(size_t)(col0 + c) * D + kq * 4];
        sBT[kq * 4 + 0][c] = v.x;
        sBT[kq * 4 + 1][c] = v.y;
        sBT[kq * 4 + 2][c] = v.z;
        sBT[kq * 4 + 3][c] = v.w;
    }
    __syncthreads();

    int cg2 = tid & 15;   // cols cg2*4..+4
    int rg = tid >> 4;    // rows rg*4..+4
    float acc[4][4] = {};
    #pragma unroll 2
    for (int k = 0; k < 128; ++k) {
        float4 a = *(const float4*)&sAT[k][rg * 4];
        float4 b = *(const float4*)&sBT[k][cg2 * 4];
        acc[0][0] += a.x * b.x; acc[0][1] += a.x * b.y; acc[0][2] += a.x * b.z; acc[0][3] += a.x * b.w;
        acc[1][0] += a.y * b.x; acc[1][1] += a.y * b.y; acc[1][2] += a.y * b.z; acc[1][3] += a.y * b.w;
        acc[2][0] += a.z * b.x; acc[2][1] += a.z * b.y; acc[2][2] += a.z * b.z; acc[2][3] += a.z * b.w;
        acc[3][0] += a.w * b.x; acc[3][1] += a.w * b.y; acc[3][2] += a.w * b.z; acc[3][3] += a.w * b.w;
    }

    float4 bv = *(const float4*)&bias[col0 + cg2 * 4];
    #pragma unroll
    for (int i = 0; i < 4; ++i) {
        int r = row0 + rg * 4 + i;
        if (r < N_NODES) {
            float4 ov = make_float4(acc[i][0] + bv.x, acc[i][1] + bv.y,
                                    acc[i][2] + bv.z, acc[i][3] + bv.w);
            *(float4*)&out[(size_t)r * D + col0 + cg2 * 4] = ov;
        }
    }
}

extern "C" void kernel_launch(void* const* d_in, const int* in_sizes, int n_in,
                              void* d_out, int out_size, void* d_ws, size_t ws_size,
                              hipStream_t stream) {
    const float* node_emb = (const float*)d_in[0];
    const int*   edge     = (const int*)d_in[1];   // [2,E]: row 0 = src, row 1 = dst
    const float* weight   = (const float*)d_in[2]; // [D_OUT, D_IN] row-major
    const float* bias     = (const float*)d_in[3];
    float* out = (float*)d_out;

    char* ws = (char*)d_ws;
    float*        hbuf = (float*)ws;        ws += (size_t)N_NODES * D * sizeof(float);
    unsigned int* xb0  = (unsigned int*)ws; ws += (size_t)N_NODES * 64 * sizeof(unsigned int);
    unsigned int* xb1  = (unsigned int*)ws; ws += (size_t)N_NODES * 64 * sizeof(unsigned int);
    int2*  csr      = (int2*)ws;  ws += (size_t)N_EDGES * sizeof(int2);
    int*   rank     = (int*)ws;   ws += (size_t)N_EDGES * sizeof(int);
    int*   deg      = (int*)ws;   ws += (size_t)N_NODES * sizeof(int);
    int*   row_start= (int*)ws;   ws += (size_t)(N_NODES + 1) * sizeof(int);
    float* dinv     = (float*)ws; ws += (size_t)N_NODES * sizeof(float);
    float* selfw    = (float*)ws; ws += (size_t)N_NODES * sizeof(float);

    const int* srcp = edge;
    const int* dstp = edge + N_EDGES;

    hipMemsetAsync(deg, 0, N_NODES * sizeof(int), stream);

    deg_kernel<<<(N_EDGES + 255) / 256, 256, 0, stream>>>(dstp, deg, rank, N_EDGES);
    dinv_kernel<<<(N_NODES + 255) / 256, 256, 0, stream>>>(deg, dinv, selfw, N_NODES);
    scan_kernel<<<1, 1024, 0, stream>>>(deg, row_start, N_NODES);
    scatter_kernel<<<(N_EDGES + 255) / 256, 256, 0, stream>>>(srcp, dstp, rank, row_start,
                                                              csr, dinv, N_EDGES);

    // Try the cooperative persistent-hop kernel (init + 16 hops + h writeback, one dispatch).
    const float2* x0c = (const float2*)node_emb;
    float2* houtc = (float2*)hbuf;
    void* args[] = {(void*)&x0c, (void*)&xb0, (void*)&xb1, (void*)&houtc,
                    (void*)&selfw, (void*)&row_start, (void*)&csr};
    hipError_t cerr = hipLaunchCooperativeKernel((void*)hops_kernel, dim3(NBLOCKS), dim3(256),
                                                 args, 0, stream);
    if (cerr != hipSuccess) {
        // Fallback: proven R7 multi-launch path (identical semantics, h -> hbuf).
        int n2 = N_NODES * D / 2;
        init_kernel<<<(n2 + 255) / 256, 256, 0, stream>>>((const float2*)node_emb, xb0,
                                                          (float2*)hbuf, n2);
        unsigned int* cur = xb0;
        unsigned int* nxt = xb1;
        for (int k = 0; k < K_HOPS; ++k) {
            agg_kernel<<<(N_NODES + 3) / 4, 256, 0, stream>>>(cur, nxt, (float2*)hbuf,
                                                              selfw, row_start, csr, k & 1);
            unsigned int* tmp = cur; cur = nxt; nxt = tmp;
        }
    }

    // Out-of-place GEMM: reads hbuf (f32), writes d_out.
    dim3 ggrid((N_NODES + 63) / 64, 2);
    gemm_kernel<<<ggrid, 256, 0, stream>>>(hbuf, weight, bias, out);
}

// Round 10
// 1118.334 us; speedup vs baseline: 3.5032x; 3.5032x over previous
//
#include <hip/hip_runtime.h>

// SSGC: h = alpha*x0 + (1-alpha)/K * sum_{k=1..K} (D^-1/2 A_hat D^-1/2)^k x0 ; out = h W^T + b
// N=50000, E=1.6M, D=128, K=16, alpha=0.05.
// R10: back to the proven R7 multi-launch structure (coop/persistent abandoned: R9 showed
//      register spills + no structural headroom). New: u16 edge records (src only, 2B/edge;
//      weight recomputed in agg as dinv[d]*dinv[s] from the L2-resident 200KB dinv table)
//      — exact arithmetic, -9.6 MB/hop fabric traffic. bf16 feature rows, stepped gather
//      tails, h RMW every 2 hops, register-tiled f32 GEMM.

#define N_NODES 50000
#define N_EDGES 1600000
#define D 128
#define K_HOPS 16
#define ALPHA 0.05f
#define HCOEF ((1.0f - ALPHA) / (float)K_HOPS)

__device__ __forceinline__ unsigned int f2bf(float f) {
    unsigned int u = __float_as_uint(f);
    return (u + 0x7FFFu + ((u >> 16) & 1u)) >> 16;   // RNE
}
__device__ __forceinline__ unsigned int pack_bf2(float x, float y) {
    return f2bf(x) | (f2bf(y) << 16);
}
__device__ __forceinline__ float bf_lo(unsigned int w) { return __uint_as_float(w << 16); }
__device__ __forceinline__ float bf_hi(unsigned int w) { return __uint_as_float(w & 0xFFFF0000u); }

// Count in-degree and assign each edge its within-destination rank (coalesced write).
__global__ void deg_kernel(const int* __restrict__ dst, int* __restrict__ deg,
                           int* __restrict__ rank, int e) {
    int i = blockIdx.x * blockDim.x + threadIdx.x;
    if (i < e) rank[i] = atomicAdd(&deg[dst[i]], 1);
}

// dinv = 1/sqrt(deg+1)
__global__ void dinv_kernel(const int* __restrict__ deg, float* __restrict__ dinv, int n) {
    int i = blockIdx.x * blockDim.x + threadIdx.x;
    if (i < n) dinv[i] = rsqrtf((float)(deg[i] + 1));
}

// Exclusive scan of deg -> row_start. Single block, 1024 threads, shfl wave scans.
__global__ void scan_kernel(const int* __restrict__ deg, int* __restrict__ row_start, int n) {
    __shared__ int wsum[16];
    __shared__ int tot_s;
    __shared__ int carry_s;
    int tid = threadIdx.x, lane = tid & 63, wid = tid >> 6;
    if (tid == 0) carry_s = 0;
    __syncthreads();
    for (int base = 0; base < n; base += 1024) {
        int i = base + tid;
        int v = (i < n) ? deg[i] : 0;
        int s = v;
        #pragma unroll
        for (int off = 1; off < 64; off <<= 1) {
            int t = __shfl_up(s, off, 64);
            if (lane >= off) s += t;
        }
        if (lane == 63) wsum[wid] = s;
        __syncthreads();                       // (A) wsum ready
        if (tid == 0) {
            int run = 0;
            #pragma unroll
            for (int w = 0; w < 16; ++w) { int t = wsum[w]; wsum[w] = run; run += t; }
            tot_s = run;
        }
        __syncthreads();                       // (B) offsets ready, carry stable
        if (i < n) row_start[i] = carry_s + wsum[wid] + (s - v);
        __syncthreads();                       // (C) all reads of carry_s done
        if (tid == 0) carry_s += tot_s;
    }
    __syncthreads();
    if (tid == 0) row_start[n] = carry_s;
}

// One 2B scattered store per edge: record = src as u16 (N < 65536).
__global__ void scatter_kernel(const int* __restrict__ src, const int* __restrict__ dst,
                               const int* __restrict__ rank,
                               const int* __restrict__ row_start,
                               unsigned short* __restrict__ csr16, int e) {
    int i = blockIdx.x * blockDim.x + threadIdx.x;
    if (i < e) {
        int d = dst[i];
        int pos = row_start[d] + rank[i];
        csr16[pos] = (unsigned short)src[i];
    }
}

// x0 -> packed bf16 x; h = alpha * x0 (exact f32).
__global__ void init_kernel(const float2* __restrict__ x0, unsigned int* __restrict__ xb,
                            float2* __restrict__ h, int n2) {
    int i = blockIdx.x * blockDim.x + threadIdx.x;
    if (i < n2) {
        float2 v = x0[i];
        xb[i] = pack_bf2(v.x, v.y);
        h[i] = make_float2(ALPHA * v.x, ALPHA * v.y);
    }
}

#define GATHER_BLOCK(W)                                                         \
    {                                                                           \
        unsigned int g[W];                                                      \
        float wv[W];                                                            \
        _Pragma("unroll") for (int q = 0; q < W; ++q) {                         \
            int s = __shfl(rec_s, j + q);                                       \
            wv[q] = __shfl(wlane, j + q);                                       \
            g[q] = xb[(size_t)s * 64 + lane];                                   \
        }                                                                       \
        _Pragma("unroll") for (int q = 0; q < W; ++q) {                         \
            accx += wv[q] * bf_lo(g[q]);                                        \
            accy += wv[q] * bf_hi(g[q]);                                        \
        }                                                                       \
        j += W;                                                                 \
    }

// One wave (64 lanes) per node; lane owns features [2*lane, 2*lane+1] (one packed dword).
// u16 edge records loaded 64-at-a-time coalesced; per-edge weight di*dinv[s] computed at
// batch load (dinv table is L2-resident); broadcast with shfl; stepped unroll 16/8/4.
// update_h: h += c*(x_k + x_{k+1}) using the rounded self-row (x_k) + fresh acc (x_{k+1}).
__global__ __launch_bounds__(256) void agg_kernel(
    const unsigned int* __restrict__ xb, unsigned int* __restrict__ yb,
    float2* __restrict__ h2, const float* __restrict__ dinv,
    const int* __restrict__ row_start, const unsigned short* __restrict__ csr16,
    int update_h) {
    int wid = threadIdx.x >> 6;
    int lane = threadIdx.x & 63;
    int node = blockIdx.x * 4 + wid;
    if (node >= N_NODES) return;

    int r0 = row_start[node];
    int r1 = row_start[node + 1];
    int deg = r1 - r0;
    size_t o = (size_t)node * 64 + lane;

    unsigned int vw = xb[o];
    float di = dinv[node];
    float accx = di * di * bf_lo(vw), accy = di * di * bf_hi(vw);   // self loop

    for (int base = 0; base < deg; base += 64) {
        int cnt = deg - base;
        if (cnt > 64) cnt = 64;
        int idx = r0 + base + lane;
        if (idx >= r1) idx = r1 - 1;           // clamped lanes are never shfl-read
        int rec_s = (int)csr16[idx];           // one coalesced 2B/lane load per wave
        float wlane = di * dinv[rec_s];        // exact norm weight; dinv gather hits L2;
                                               // x-gathers depend only on rec_s, not wlane

        int j = 0;
        while (j + 16 <= cnt) GATHER_BLOCK(16);
        if (j + 8 <= cnt) GATHER_BLOCK(8);
        if (j + 4 <= cnt) GATHER_BLOCK(4);
        for (; j < cnt; ++j) {
            int s = __shfl(rec_s, j);
            float w = __shfl(wlane, j);
            unsigned int gw = xb[(size_t)s * 64 + lane];
            accx += w * bf_lo(gw);
            accy += w * bf_hi(gw);
        }
    }

    yb[o] = pack_bf2(accx, accy);              // bf16 state for next hop
    if (update_h) {
        float2 hv = h2[o];
        hv.x += HCOEF * (bf_lo(vw) + accx);    // x_k (rounded) + x_{k+1} (pre-round)
        hv.y += HCOEF * (bf_hi(vw) + accy);
        h2[o] = hv;
    }
}

// out[r][c] = sum_k h[r][k]*W[c][k] + bias[c]. h and out are DIFFERENT buffers.
// Block: 64 rows x 64 cols, 256 threads, 4x4 acc/thread. k-major LDS tiles.
__global__ __launch_bounds__(256) void gemm_kernel(
    const float* __restrict__ h, const float* __restrict__ w,
    const float* __restrict__ bias, float* __restrict__ out) {
    __shared__ float sAT[128][64];   // [k][row]
    __shared__ float sBT[128][64];   // [k][col]
    int tid = threadIdx.x;
    int row0 = blockIdx.x * 64;
    int col0 = blockIdx.y * 64;

    for (int idx = tid; idx < 64 * 32; idx += 256) {
        int r = idx & 63, kq = idx >> 6;
        float4 v;
        if (row0 + r < N_NODES)
            v = *(const float4*)&h[(size_t)(row0 + r) * D + kq * 4];
        else
            v = make_float4(0.f, 0.f, 0.f, 0.f);
        sAT[kq * 4 + 0][r] = v.x;
        sAT[kq * 4 + 1][r] = v.y;
        sAT[kq * 4 + 2][r] = v.z;
        sAT[kq * 4 + 3][r] = v.w;
    }
    for (int idx = tid; idx < 64 * 32; idx += 256) {
        int c = idx & 63, kq = idx >> 6;
        float4 v = *(const float4*)&w[(size_t)(col0 + c) * D + kq * 4];
        sBT[kq * 4 + 0][c] = v.x;
        sBT[kq * 4 + 1][c] = v.y;
        sBT[kq * 4 + 2][c] = v.z;
        sBT[kq * 4 + 3][c] = v.w;
    }
    __syncthreads();

    int cg = tid & 15;    // cols cg*4..+4
    int rg = tid >> 4;    // rows rg*4..+4
    float acc[4][4] = {};
    #pragma unroll 2
    for (int k = 0; k < 128; ++k) {
        float4 a = *(const float4*)&sAT[k][rg * 4];
        float4 b = *(const float4*)&sBT[k][cg * 4];
        acc[0][0] += a.x * b.x; acc[0][1] += a.x * b.y; acc[0][2] += a.x * b.z; acc[0][3] += a.x * b.w;
        acc[1][0] += a.y * b.x; acc[1][1] += a.y * b.y; acc[1][2] += a.y * b.z; acc[1][3] += a.y * b.w;
        acc[2][0] += a.z * b.x; acc[2][1] += a.z * b.y; acc[2][2] += a.z * b.z; acc[2][3] += a.z * b.w;
        acc[3][0] += a.w * b.x; acc[3][1] += a.w * b.y; acc[3][2] += a.w * b.z; acc[3][3] += a.w * b.w;
    }

    float4 bv = *(const float4*)&bias[col0 + cg * 4];
    #pragma unroll
    for (int i = 0; i < 4; ++i) {
        int r = row0 + rg * 4 + i;
        if (r < N_NODES) {
            float4 ov = make_float4(acc[i][0] + bv.x, acc[i][1] + bv.y,
                                    acc[i][2] + bv.z, acc[i][3] + bv.w);
            *(float4*)&out[(size_t)r * D + col0 + cg * 4] = ov;
        }
    }
}

extern "C" void kernel_launch(void* const* d_in, const int* in_sizes, int n_in,
                              void* d_out, int out_size, void* d_ws, size_t ws_size,
                              hipStream_t stream) {
    const float* node_emb = (const float*)d_in[0];
    const int*   edge     = (const int*)d_in[1];   // [2,E]: row 0 = src, row 1 = dst
    const float* weight   = (const float*)d_in[2]; // [D_OUT, D_IN] row-major
    const float* bias     = (const float*)d_in[3];
    float* out = (float*)d_out;

    char* ws = (char*)d_ws;
    float*          hbuf  = (float*)ws;          ws += (size_t)N_NODES * D * sizeof(float);
    unsigned int*   xb0   = (unsigned int*)ws;   ws += (size_t)N_NODES * 64 * sizeof(unsigned int);
    unsigned int*   xb1   = (unsigned int*)ws;   ws += (size_t)N_NODES * 64 * sizeof(unsigned int);
    int*            rank  = (int*)ws;            ws += (size_t)N_EDGES * sizeof(int);
    unsigned short* csr16 = (unsigned short*)ws; ws += (size_t)N_EDGES * sizeof(unsigned short);
    int*   deg      = (int*)ws;   ws += (size_t)N_NODES * sizeof(int);
    int*   row_start= (int*)ws;   ws += (size_t)(N_NODES + 1) * sizeof(int);
    float* dinv     = (float*)ws; ws += (size_t)N_NODES * sizeof(float);

    const int* srcp = edge;
    const int* dstp = edge + N_EDGES;

    hipMemsetAsync(deg, 0, N_NODES * sizeof(int), stream);

    deg_kernel<<<(N_EDGES + 255) / 256, 256, 0, stream>>>(dstp, deg, rank, N_EDGES);
    dinv_kernel<<<(N_NODES + 255) / 256, 256, 0, stream>>>(deg, dinv, N_NODES);
    scan_kernel<<<1, 1024, 0, stream>>>(deg, row_start, N_NODES);
    scatter_kernel<<<(N_EDGES + 255) / 256, 256, 0, stream>>>(srcp, dstp, rank, row_start,
                                                              csr16, N_EDGES);

    int n2 = N_NODES * D / 2;
    init_kernel<<<(n2 + 255) / 256, 256, 0, stream>>>((const float2*)node_emb, xb0,
                                                      (float2*)hbuf, n2);

    unsigned int* cur = xb0;
    unsigned int* nxt = xb1;
    for (int k = 0; k < K_HOPS; ++k) {
        agg_kernel<<<(N_NODES + 3) / 4, 256, 0, stream>>>(cur, nxt, (float2*)hbuf,
                                                          dinv, row_start, csr16, k & 1);
        unsigned int* tmp = cur; cur = nxt; nxt = tmp;
    }

    // Out-of-place GEMM: reads hbuf (f32), writes d_out.
    dim3 ggrid((N_NODES + 63) / 64, 2);
    gemm_kernel<<<ggrid, 256, 0, stream>>>(hbuf, weight, bias, out);
}

// Round 11
// 1105.646 us; speedup vs baseline: 3.5434x; 1.0115x over previous
//
#include <hip/hip_runtime.h>

// SSGC: h = alpha*x0 + (1-alpha)/K * sum_{k=1..K} (D^-1/2 A_hat D^-1/2)^k x0 ; out = h W^T + b
// N=50000, E=1.6M, D=128, K=16, alpha=0.05.
// R11 (final tuning): R7-proven int2 edge records (u16+dinv-recompute reverted: the per-edge
//     dinv gather cost more than the byte saving), h RMW every 3 hops (reads x_{k-1} from
//     the nxt buffer pre-overwrite; x_16 folded into GEMM staging), dinv/selfw computed in
//     the scan kernel. bf16 feature rows, stepped gather tails, register-tiled f32 GEMM.
// agg is at the measured random-gather fabric ceiling (~3.4-3.8 TB/s L2-miss traffic,
// byte-proportional f32->bf16 scaling); bf16 is the accuracy floor for the 6.25e-3 budget.

#define N_NODES 50000
#define N_EDGES 1600000
#define D 128
#define K_HOPS 16
#define ALPHA 0.05f
#define HCOEF ((1.0f - ALPHA) / (float)K_HOPS)

__device__ __forceinline__ unsigned int f2bf(float f) {
    unsigned int u = __float_as_uint(f);
    return (u + 0x7FFFu + ((u >> 16) & 1u)) >> 16;   // RNE
}
__device__ __forceinline__ unsigned int pack_bf2(float x, float y) {
    return f2bf(x) | (f2bf(y) << 16);
}
__device__ __forceinline__ float bf_lo(unsigned int w) { return __uint_as_float(w << 16); }
__device__ __forceinline__ float bf_hi(unsigned int w) { return __uint_as_float(w & 0xFFFF0000u); }

// Count in-degree and assign each edge its within-destination rank (coalesced write).
__global__ void deg_kernel(const int* __restrict__ dst, int* __restrict__ deg,
                           int* __restrict__ rank, int e) {
    int i = blockIdx.x * blockDim.x + threadIdx.x;
    if (i < e) rank[i] = atomicAdd(&deg[dst[i]], 1);
}

// Exclusive scan of deg -> row_start; also emits dinv = 1/sqrt(deg+1), selfw = 1/(deg+1).
__global__ void scan_kernel(const int* __restrict__ deg, int* __restrict__ row_start,
                            float* __restrict__ dinv, float* __restrict__ selfw, int n) {
    __shared__ int wsum[16];
    __shared__ int tot_s;
    __shared__ int carry_s;
    int tid = threadIdx.x, lane = tid & 63, wid = tid >> 6;
    if (tid == 0) carry_s = 0;
    __syncthreads();
    for (int base = 0; base < n; base += 1024) {
        int i = base + tid;
        int v = (i < n) ? deg[i] : 0;
        if (i < n) {
            float di = rsqrtf((float)(v + 1));
            dinv[i] = di;
            selfw[i] = 1.0f / (float)(v + 1);
        }
        int s = v;
        #pragma unroll
        for (int off = 1; off < 64; off <<= 1) {
            int t = __shfl_up(s, off, 64);
            if (lane >= off) s += t;
        }
        if (lane == 63) wsum[wid] = s;
        __syncthreads();                       // (A) wsum ready
        if (tid == 0) {
            int run = 0;
            #pragma unroll
            for (int w = 0; w < 16; ++w) { int t = wsum[w]; wsum[w] = run; run += t; }
            tot_s = run;
        }
        __syncthreads();                       // (B) offsets ready, carry stable
        if (i < n) row_start[i] = carry_s + wsum[wid] + (s - v);
        __syncthreads();                       // (C) all reads of carry_s done
        if (tid == 0) carry_s += tot_s;
    }
    __syncthreads();
    if (tid == 0) row_start[n] = carry_s;
}

// One 8B scattered store per edge: record = (src, bitcast(norm weight)).
__global__ void scatter_kernel(const int* __restrict__ src, const int* __restrict__ dst,
                               const int* __restrict__ rank,
                               const int* __restrict__ row_start, int2* __restrict__ csr,
                               const float* __restrict__ dinv, int e) {
    int i = blockIdx.x * blockDim.x + threadIdx.x;
    if (i < e) {
        int d = dst[i];
        int s = src[i];
        int pos = row_start[d] + rank[i];
        csr[pos] = make_int2(s, __float_as_int(dinv[d] * dinv[s]));
    }
}

// x0 -> packed bf16 x; h = alpha * x0 (exact f32).
__global__ void init_kernel(const float2* __restrict__ x0, unsigned int* __restrict__ xb,
                            float2* __restrict__ h, int n2) {
    int i = blockIdx.x * blockDim.x + threadIdx.x;
    if (i < n2) {
        float2 v = x0[i];
        xb[i] = pack_bf2(v.x, v.y);
        h[i] = make_float2(ALPHA * v.x, ALPHA * v.y);
    }
}

#define GATHER_BLOCK(W)                                                         \
    {                                                                           \
        unsigned int g[W];                                                      \
        float wv[W];                                                            \
        _Pragma("unroll") for (int q = 0; q < W; ++q) {                         \
            int s = __shfl(rec.x, j + q);                                       \
            wv[q] = __int_as_float(__shfl(rec.y, j + q));                       \
            g[q] = xb[(size_t)s * 64 + lane];                                   \
        }                                                                       \
        _Pragma("unroll") for (int q = 0; q < W; ++q) {                         \
            accx += wv[q] * bf_lo(g[q]);                                        \
            accy += wv[q] * bf_hi(g[q]);                                        \
        }                                                                       \
        j += W;                                                                 \
    }

// One wave (64 lanes) per node; lane owns features [2*lane, 2*lane+1] (one packed dword).
// Edge records loaded 64-at-a-time coalesced, broadcast with shfl; stepped unroll 16/8/4.
// update_h: h += c*(x_{k-1} + x_k + x_{k+1}); x_{k-1} read from yb before overwrite,
// x_k from the self row (rounded), x_{k+1} from the fresh f32 accumulator.
__global__ __launch_bounds__(256) void agg_kernel(
    const unsigned int* __restrict__ xb, unsigned int* __restrict__ yb,
    float2* __restrict__ h2, const float* __restrict__ selfw,
    const int* __restrict__ row_start, const int2* __restrict__ csr, int update_h) {
    int wid = threadIdx.x >> 6;
    int lane = threadIdx.x & 63;
    int node = blockIdx.x * 4 + wid;
    if (node >= N_NODES) return;

    int r0 = row_start[node];
    int r1 = row_start[node + 1];
    int deg = r1 - r0;
    size_t o = (size_t)node * 64 + lane;

    unsigned int vw = xb[o];
    float sw = selfw[node];
    float accx = sw * bf_lo(vw), accy = sw * bf_hi(vw);

    for (int base = 0; base < deg; base += 64) {
        int cnt = deg - base;
        if (cnt > 64) cnt = 64;
        int idx = r0 + base + lane;
        if (idx >= r1) idx = r1 - 1;           // clamped lanes are never shfl-read
        int2 rec = csr[idx];                   // one coalesced dwordx2 per wave

        int j = 0;
        while (j + 16 <= cnt) GATHER_BLOCK(16);
        if (j + 8 <= cnt) GATHER_BLOCK(8);
        if (j + 4 <= cnt) GATHER_BLOCK(4);
        for (; j < cnt; ++j) {
            int s = __shfl(rec.x, j);
            float w = __int_as_float(__shfl(rec.y, j));
            unsigned int gw = xb[(size_t)s * 64 + lane];
            accx += w * bf_lo(gw);
            accy += w * bf_hi(gw);
        }
    }

    if (update_h) {
        unsigned int pw = yb[o];               // x_{k-1} (rounded), read before overwrite
        float2 hv = h2[o];
        hv.x += HCOEF * (bf_lo(pw) + bf_lo(vw) + accx);
        hv.y += HCOEF * (bf_hi(pw) + bf_hi(vw) + accy);
        h2[o] = hv;
    }
    yb[o] = pack_bf2(accx, accy);              // bf16 state for next hop
}

// out[r][c] = sum_k (h[r][k] + HCOEF*bf16(xfin[r][k])) * W[c][k] + bias[c].
// xfin = x_16 (final hop state), folding the last h term into the GEMM.
// Block: 64 rows x 64 cols, 256 threads, 4x4 acc/thread. k-major LDS tiles.
__global__ __launch_bounds__(256) void gemm_kernel(
    const float* __restrict__ h, const unsigned int* __restrict__ xfin,
    const float* __restrict__ w, const float* __restrict__ bias, float* __restrict__ out) {
    __shared__ float sAT[128][64];   // [k][row]
    __shared__ float sBT[128][64];   // [k][col]
    int tid = threadIdx.x;
    int row0 = blockIdx.x * 64;
    int col0 = blockIdx.y * 64;

    for (int idx = tid; idx < 64 * 32; idx += 256) {
        int r = idx & 63, kq = idx >> 6;
        float4 v = make_float4(0.f, 0.f, 0.f, 0.f);
        if (row0 + r < N_NODES) {
            v = *(const float4*)&h[(size_t)(row0 + r) * D + kq * 4];
            uint2 xw = *(const uint2*)&xfin[(size_t)(row0 + r) * 64 + kq * 2];
            v.x += HCOEF * bf_lo(xw.x);
            v.y += HCOEF * bf_hi(xw.x);
            v.z += HCOEF * bf_lo(xw.y);
            v.w += HCOEF * bf_hi(xw.y);
        }
        sAT[kq * 4 + 0][r] = v.x;
        sAT[kq * 4 + 1][r] = v.y;
        sAT[kq * 4 + 2][r] = v.z;
        sAT[kq * 4 + 3][r] = v.w;
    }
    for (int idx = tid; idx < 64 * 32; idx += 256) {
        int c = idx & 63, kq = idx >> 6;
        float4 v = *(const float4*)&w[(size_t)(col0 + c) * D + kq * 4];
        sBT[kq * 4 + 0][c] = v.x;
        sBT[kq * 4 + 1][c] = v.y;
        sBT[kq * 4 + 2][c] = v.z;
        sBT[kq * 4 + 3][c] = v.w;
    }
    __syncthreads();

    int cg = tid & 15;    // cols cg*4..+4
    int rg = tid >> 4;    // rows rg*4..+4
    float acc[4][4] = {};
    #pragma unroll 2
    for (int k = 0; k < 128; ++k) {
        float4 a = *(const float4*)&sAT[k][rg * 4];
        float4 b = *(const float4*)&sBT[k][cg * 4];
        acc[0][0] += a.x * b.x; acc[0][1] += a.x * b.y; acc[0][2] += a.x * b.z; acc[0][3] += a.x * b.w;
        acc[1][0] += a.y * b.x; acc[1][1] += a.y * b.y; acc[1][2] += a.y * b.z; acc[1][3] += a.y * b.w;
        acc[2][0] += a.z * b.x; acc[2][1] += a.z * b.y; acc[2][2] += a.z * b.z; acc[2][3] += a.z * b.w;
        acc[3][0] += a.w * b.x; acc[3][1] += a.w * b.y; acc[3][2] += a.w * b.z; acc[3][3] += a.w * b.w;
    }

    float4 bv = *(const float4*)&bias[col0 + cg * 4];
    #pragma unroll
    for (int i = 0; i < 4; ++i) {
        int r = row0 + rg * 4 + i;
        if (r < N_NODES) {
            float4 ov = make_float4(acc[i][0] + bv.x, acc[i][1] + bv.y,
                                    acc[i][2] + bv.z, acc[i][3] + bv.w);
            *(float4*)&out[(size_t)r * D + col0 + cg * 4] = ov;
        }
    }
}

extern "C" void kernel_launch(void* const* d_in, const int* in_sizes, int n_in,
                              void* d_out, int out_size, void* d_ws, size_t ws_size,
                              hipStream_t stream) {
    const float* node_emb = (const float*)d_in[0];
    const int*   edge     = (const int*)d_in[1];   // [2,E]: row 0 = src, row 1 = dst
    const float* weight   = (const float*)d_in[2]; // [D_OUT, D_IN] row-major
    const float* bias     = (const float*)d_in[3];
    float* out = (float*)d_out;

    char* ws = (char*)d_ws;
    float*        hbuf = (float*)ws;        ws += (size_t)N_NODES * D * sizeof(float);
    unsigned int* xb0  = (unsigned int*)ws; ws += (size_t)N_NODES * 64 * sizeof(unsigned int);
    unsigned int* xb1  = (unsigned int*)ws; ws += (size_t)N_NODES * 64 * sizeof(unsigned int);
    int2*  csr      = (int2*)ws;  ws += (size_t)N_EDGES * sizeof(int2);
    int*   rank     = (int*)ws;   ws += (size_t)N_EDGES * sizeof(int);
    int*   deg      = (int*)ws;   ws += (size_t)N_NODES * sizeof(int);
    int*   row_start= (int*)ws;   ws += (size_t)(N_NODES + 1) * sizeof(int);
    float* dinv     = (float*)ws; ws += (size_t)N_NODES * sizeof(float);
    float* selfw    = (float*)ws; ws += (size_t)N_NODES * sizeof(float);

    const int* srcp = edge;
    const int* dstp = edge + N_EDGES;

    hipMemsetAsync(deg, 0, N_NODES * sizeof(int), stream);

    deg_kernel<<<(N_EDGES + 255) / 256, 256, 0, stream>>>(dstp, deg, rank, N_EDGES);
    scan_kernel<<<1, 1024, 0, stream>>>(deg, row_start, dinv, selfw, N_NODES);
    scatter_kernel<<<(N_EDGES + 255) / 256, 256, 0, stream>>>(srcp, dstp, rank, row_start,
                                                              csr, dinv, N_EDGES);

    int n2 = N_NODES * D / 2;
    init_kernel<<<(n2 + 255) / 256, 256, 0, stream>>>((const float2*)node_emb, xb0,
                                                      (float2*)hbuf, n2);

    unsigned int* cur = xb0;
    unsigned int* nxt = xb1;
    for (int k = 0; k < K_HOPS; ++k) {
        int upd = (k % 3 == 2) ? 1 : 0;        // hops 2,5,8,11,14 -> h covers x_1..x_15
        agg_kernel<<<(N_NODES + 3) / 4, 256, 0, stream>>>(cur, nxt, (float2*)hbuf,
                                                          selfw, row_start, csr, upd);
        unsigned int* tmp = cur; cur = nxt; nxt = tmp;
    }

    // GEMM reads hbuf + folds the missing c*x_16 term from cur (final hop state).
    dim3 ggrid((N_NODES + 63) / 64, 2);
    gemm_kernel<<<ggrid, 256, 0, stream>>>(hbuf, cur, weight, bias, out);
}